// Round 1
// baseline (42284.909 us; speedup 1.0000x reference)
//
#include <hip/hip_runtime.h>
#include <hip/hip_bf16.h>
#include <math.h>

#define HID    512
#define BATCH  256
#define TLEN   512
#define FUT    16
#define NSTEP  (TLEN + FUT)   // 528
#define NGRP   8              // batch groups (one per XCD ideally)
#define WPG    32             // workgroups per group
#define BPG    32             // batch per group
#define UPW    16             // hidden units per WG
#define NR     64             // gate rows per WG (4 gates * UPW)

// workspace byte offsets (all 256-aligned)
#define OFF_W0   0u           // packed Whh0 slices  [32][64][512]  bf16 = 2 MB
#define OFF_W1   2097152u     // packed [Wih1|Whh1]  [32][64][1024] bf16 = 4 MB
#define OFF_CA   6291456u     // activations [grp][2][32][1024] bf16 = 1 MB
#define OFF_XF   7340032u     // feedback outs [FUT+1][256] f32
#define OFF_WI   7357440u     // Wih0 col packed [32][64] f32
#define OFF_B0   7365632u     // bih0+bhh0 packed [32][64] f32
#define OFF_B1   7373824u     // bih1+bhh1 packed [32][64] f32
#define OFF_BAR  7382016u     // 8 groups * 64 uints barrier state

typedef __bf16 bf16x8 __attribute__((ext_vector_type(8)));
typedef float  f32x4  __attribute__((ext_vector_type(4)));

__device__ __forceinline__ float sigf(float v)      { return 1.f / (1.f + __expf(-v)); }
__device__ __forceinline__ float tanh_fast(float v) { return 2.f / (1.f + __expf(-2.f * v)) - 1.f; }

__device__ __forceinline__ void group_barrier(unsigned* bar, unsigned target) {
    __syncthreads();
    if (threadIdx.x == 0) {
        unsigned arr = __hip_atomic_fetch_add(&bar[0], 1u, __ATOMIC_ACQ_REL, __HIP_MEMORY_SCOPE_AGENT);
        if (arr == WPG - 1) {
            __hip_atomic_store(&bar[0], 0u, __ATOMIC_RELAXED, __HIP_MEMORY_SCOPE_AGENT);
            __hip_atomic_fetch_add(&bar[1], 1u, __ATOMIC_RELEASE, __HIP_MEMORY_SCOPE_AGENT);
        } else {
            while (__hip_atomic_load(&bar[1], __ATOMIC_ACQUIRE, __HIP_MEMORY_SCOPE_AGENT) < target) {
                __builtin_amdgcn_s_sleep(2);
            }
        }
    }
    __syncthreads();
}

__global__ void lstm_init(char* __restrict__ ws, float* __restrict__ out,
                          const float* __restrict__ blin)
{
    float bl = blin[0];
    int tid = blockIdx.x * blockDim.x + threadIdx.x;
    int stride = gridDim.x * blockDim.x;
    uint4* ca = (uint4*)(ws + OFF_CA);
    for (int i = tid; i < 65536; i += stride) ca[i] = make_uint4(0u, 0u, 0u, 0u);
    float* xf = (float*)(ws + OFF_XF);
    for (int i = tid; i < (FUT + 1) * BATCH; i += stride) xf[i] = bl;
    unsigned* bar = (unsigned*)(ws + OFF_BAR);
    for (int i = tid; i < NGRP * 64; i += stride) bar[i] = 0u;
    for (int i = tid; i < BATCH * NSTEP; i += stride) out[i] = bl;
}

__global__ void lstm_pack(char* __restrict__ ws,
    const float* __restrict__ Wih0, const float* __restrict__ Whh0,
    const float* __restrict__ bih0, const float* __restrict__ bhh0,
    const float* __restrict__ Wih1, const float* __restrict__ Whh1,
    const float* __restrict__ bih1, const float* __restrict__ bhh1)
{
    int tid = blockIdx.x * blockDim.x + threadIdx.x;
    int stride = gridDim.x * blockDim.x;

    __hip_bfloat16* W0p = (__hip_bfloat16*)(ws + OFF_W0);
    for (int i = tid; i < 32 * 64 * 512; i += stride) {
        int k = i & 511, r = (i >> 9) & 63, m = i >> 15;
        int row = (r >> 4) * HID + m * UPW + (r & 15);
        W0p[i] = __float2bfloat16(Whh0[(size_t)row * HID + k]);
    }
    __hip_bfloat16* W1p = (__hip_bfloat16*)(ws + OFF_W1);
    for (int i = tid; i < 32 * 64 * 1024; i += stride) {
        int k = i & 1023, r = (i >> 10) & 63, m = i >> 16;
        int row = (r >> 4) * HID + m * UPW + (r & 15);
        float v = (k < 512) ? Wih1[(size_t)row * HID + k] : Whh1[(size_t)row * HID + (k - 512)];
        W1p[i] = __float2bfloat16(v);
    }
    float* wi = (float*)(ws + OFF_WI);
    float* b0 = (float*)(ws + OFF_B0);
    float* b1 = (float*)(ws + OFF_B1);
    for (int i = tid; i < 32 * 64; i += stride) {
        int r = i & 63, m = i >> 6;
        int row = (r >> 4) * HID + m * UPW + (r & 15);
        wi[i] = Wih0[row];                  // IN = 1
        b0[i] = bih0[row] + bhh0[row];
        b1[i] = bih1[row] + bhh1[row];
    }
}

__global__ __launch_bounds__(256) void lstm_persist(
    const float* __restrict__ x, const float* __restrict__ wlin,
    float* __restrict__ out, char* __restrict__ ws)
{
    const int tid  = threadIdx.x;
    const int lane = tid & 63;
    const int wave = tid >> 6;
    const int g    = blockIdx.x & 7;   // group -> XCD swizzle
    const int m    = blockIdx.x >> 3;  // member within group: unit slice
    const int bbase = g * BPG;

    __shared__ float gatesS[32][68];
    __shared__ float c0S[32][16];
    __shared__ float c1S[32][16];
    for (int i = tid; i < 32 * 16; i += 256) { c0S[i >> 4][i & 15] = 0.f; c1S[i >> 4][i & 15] = 0.f; }

    const bf16x8* W0s = (const bf16x8*)(ws + OFF_W0 + (size_t)m * NR * 512 * 2);
    const bf16x8* W1s = (const bf16x8*)(ws + OFF_W1 + (size_t)m * NR * 1024 * 2);
    const float* wis = (const float*)(ws + OFF_WI) + m * NR;
    const float* b0s = (const float*)(ws + OFF_B0) + m * NR;
    const float* b1s = (const float*)(ws + OFF_B1) + m * NR;
    __hip_bfloat16* CAbase = (__hip_bfloat16*)(ws + OFF_CA) + (size_t)g * 2 * 32 * 1024;
    float* xfeed = (float*)(ws + OFF_XF);
    unsigned* bar = (unsigned*)(ws + OFF_BAR) + g * 64;

    const int fl = lane & 15;          // n / m sub-index in fragment
    const int fq = lane >> 4;          // quad
    const int mt = wave & 1;           // batch tile (16 rows)
    const int nt0 = (wave >> 1) * 2;   // first of 2 gate tiles for this wave
    const int arow = mt * 16 + fl;
    const float wl0 = wlin[m * UPW + (tid & 15)];

    unsigned phase = 0;
    for (int t = 0; t < NSTEP; ++t) {
        const int p = t & 1;
        __hip_bfloat16* CAw = CAbase + p * (32 * 1024);
        const __hip_bfloat16* CAr = CAbase + (1 - p) * (32 * 1024);
        const bf16x8* A0 = (const bf16x8*)CAw;   // parity p   (h0 new)
        const bf16x8* A1 = (const bf16x8*)CAr;   // parity 1-p (h0 prev / h1 prev)

        // ---------------- layer 0 GEMM: gates[b][r] = sum_k h0prev[b][k] * W0[r][k]
        f32x4 acc0 = {0.f, 0.f, 0.f, 0.f}, acc1 = {0.f, 0.f, 0.f, 0.f};
#pragma unroll
        for (int ks = 0; ks < 16; ++ks) {
            bf16x8 a  = A1[arow * 128 + ks * 4 + fq];
            bf16x8 w0 = W0s[(nt0 * 16 + fl) * 64 + ks * 4 + fq];
            bf16x8 w1 = W0s[((nt0 + 1) * 16 + fl) * 64 + ks * 4 + fq];
            acc0 = __builtin_amdgcn_mfma_f32_16x16x32_bf16(a, w0, acc0, 0, 0, 0);
            acc1 = __builtin_amdgcn_mfma_f32_16x16x32_bf16(a, w1, acc1, 0, 0, 0);
        }
#pragma unroll
        for (int i = 0; i < 4; ++i) {   // C layout: m = quad*4+reg, n = lane&15
            gatesS[mt * 16 + fq * 4 + i][nt0 * 16 + fl]       = acc0[i];
            gatesS[mt * 16 + fq * 4 + i][(nt0 + 1) * 16 + fl] = acc1[i];
        }
        __syncthreads();

        // ---------------- layer 0 elementwise (fp32 state)
#pragma unroll
        for (int pp = 0; pp < 2; ++pp) {
            int b = (tid >> 4) + pp * 16;
            int us = tid & 15;
            float xv = (t < TLEN) ? x[(size_t)(bbase + b) * TLEN + t]
                                  : xfeed[(t - TLEN) * BATCH + bbase + b];
            float gi = gatesS[b][us]      + b0s[us]      + xv * wis[us];
            float gf = gatesS[b][16 + us] + b0s[16 + us] + xv * wis[16 + us];
            float gg = gatesS[b][32 + us] + b0s[32 + us] + xv * wis[32 + us];
            float go = gatesS[b][48 + us] + b0s[48 + us] + xv * wis[48 + us];
            float c = sigf(gf) * c0S[b][us] + sigf(gi) * tanh_fast(gg);
            c0S[b][us] = c;
            float h = sigf(go) * tanh_fast(c);
            CAw[b * 1024 + m * UPW + us] = __float2bfloat16(h);
        }
        __threadfence();
        ++phase;
        group_barrier(bar, phase);

        // ---------------- layer 1 GEMM: K = 1024 over [h0_new | h1_prev]
        acc0 = (f32x4){0.f, 0.f, 0.f, 0.f};
        acc1 = (f32x4){0.f, 0.f, 0.f, 0.f};
#pragma unroll
        for (int ks = 0; ks < 32; ++ks) {
            const bf16x8* Asrc = (ks < 16) ? A0 : A1;   // h0 from parity p, h1 from 1-p
            bf16x8 a  = Asrc[arow * 128 + ks * 4 + fq];
            bf16x8 w0 = W1s[(nt0 * 16 + fl) * 128 + ks * 4 + fq];
            bf16x8 w1 = W1s[((nt0 + 1) * 16 + fl) * 128 + ks * 4 + fq];
            acc0 = __builtin_amdgcn_mfma_f32_16x16x32_bf16(a, w0, acc0, 0, 0, 0);
            acc1 = __builtin_amdgcn_mfma_f32_16x16x32_bf16(a, w1, acc1, 0, 0, 0);
        }
#pragma unroll
        for (int i = 0; i < 4; ++i) {
            gatesS[mt * 16 + fq * 4 + i][nt0 * 16 + fl]       = acc0[i];
            gatesS[mt * 16 + fq * 4 + i][(nt0 + 1) * 16 + fl] = acc1[i];
        }
        __syncthreads();

        // ---------------- layer 1 elementwise + OUT=1 linear
#pragma unroll
        for (int pp = 0; pp < 2; ++pp) {
            int b = (tid >> 4) + pp * 16;
            int us = tid & 15;
            float gi = gatesS[b][us]      + b1s[us];
            float gf = gatesS[b][16 + us] + b1s[16 + us];
            float gg = gatesS[b][32 + us] + b1s[32 + us];
            float go = gatesS[b][48 + us] + b1s[48 + us];
            float c = sigf(gf) * c1S[b][us] + sigf(gi) * tanh_fast(gg);
            c1S[b][us] = c;
            float h = sigf(go) * tanh_fast(c);
            CAw[b * 1024 + 512 + m * UPW + us] = __float2bfloat16(h);
            float po = wl0 * h;
#pragma unroll
            for (int off = 1; off < 16; off <<= 1) po += __shfl_xor(po, off, 64);
            if ((lane & 15) == 0) {
                atomicAdd(&out[(size_t)(bbase + b) * NSTEP + t], po);
                if (t >= TLEN - 1)
                    atomicAdd(&xfeed[(t - (TLEN - 1)) * BATCH + bbase + b], po);
            }
        }
        __threadfence();
        ++phase;
        group_barrier(bar, phase);
    }
}

extern "C" void kernel_launch(void* const* d_in, const int* in_sizes, int n_in,
                              void* d_out, int out_size, void* d_ws, size_t ws_size,
                              hipStream_t stream)
{
    const float* x    = (const float*)d_in[0];
    const float* Wih0 = (const float*)d_in[1];
    const float* Whh0 = (const float*)d_in[2];
    const float* bih0 = (const float*)d_in[3];
    const float* bhh0 = (const float*)d_in[4];
    const float* Wih1 = (const float*)d_in[5];
    const float* Whh1 = (const float*)d_in[6];
    const float* bih1 = (const float*)d_in[7];
    const float* bhh1 = (const float*)d_in[8];
    const float* Wlin = (const float*)d_in[9];
    const float* blin = (const float*)d_in[10];
    float* out = (float*)d_out;
    char* ws = (char*)d_ws;

    hipLaunchKernelGGL(lstm_init, dim3(256), dim3(256), 0, stream, ws, out, blin);
    hipLaunchKernelGGL(lstm_pack, dim3(512), dim3(256), 0, stream,
                       ws, Wih0, Whh0, bih0, bhh0, Wih1, Whh1, bih1, bhh1);
    hipLaunchKernelGGL(lstm_persist, dim3(256), dim3(256), 0, stream, x, Wlin, out, ws);
}

// Round 2
// 23127.226 us; speedup vs baseline: 1.8284x; 1.8284x over previous
//
#include <hip/hip_runtime.h>
#include <hip/hip_bf16.h>
#include <math.h>

#define HID    512
#define BATCH  256
#define TLEN   512
#define FUT    16
#define NSTEP  (TLEN + FUT)   // 528
#define NGRP   8              // batch groups (one per XCD ideally)
#define WPG    32             // workgroups per group
#define BPG    32             // batch per group
#define UPW    16             // hidden units per WG
#define NR     64             // gate rows per WG (4 gates * UPW)

// workspace byte offsets (all 256-aligned)
#define OFF_W0   0u           // packed Whh0 slices  [32][64][512]  bf16 = 2 MB
#define OFF_W1   2097152u     // packed [Wih1|Whh1]  [32][64][1024] bf16 = 4 MB
#define OFF_CA   6291456u     // activations [grp][2][32][1024] bf16 = 1 MB
#define OFF_XF   7340032u     // feedback outs [FUT+1][256] f32
#define OFF_WI   7357440u     // Wih0 col packed [32][64] f32
#define OFF_B0   7365632u     // bih0+bhh0 packed [32][64] f32
#define OFF_B1   7373824u     // bih1+bhh1 packed [32][64] f32
#define OFF_BAR  7382016u     // 8 groups * 64 uints barrier state

typedef __bf16 bf16x8 __attribute__((ext_vector_type(8)));
typedef float  f32x4  __attribute__((ext_vector_type(4)));

__device__ __forceinline__ float sigf(float v)      { return 1.f / (1.f + __expf(-v)); }
__device__ __forceinline__ float tanh_fast(float v) { return 2.f / (1.f + __expf(-2.f * v)) - 1.f; }

__device__ __forceinline__ void group_barrier(unsigned* bar, unsigned target) {
    __syncthreads();
    if (threadIdx.x == 0) {
        unsigned arr = __hip_atomic_fetch_add(&bar[0], 1u, __ATOMIC_ACQ_REL, __HIP_MEMORY_SCOPE_AGENT);
        if (arr == WPG - 1) {
            __hip_atomic_store(&bar[0], 0u, __ATOMIC_RELAXED, __HIP_MEMORY_SCOPE_AGENT);
            __hip_atomic_fetch_add(&bar[1], 1u, __ATOMIC_RELEASE, __HIP_MEMORY_SCOPE_AGENT);
        } else {
            while (__hip_atomic_load(&bar[1], __ATOMIC_ACQUIRE, __HIP_MEMORY_SCOPE_AGENT) < target) {
                __builtin_amdgcn_s_sleep(2);
            }
        }
    }
    __syncthreads();
}

__global__ void lstm_init(char* __restrict__ ws, float* __restrict__ out,
                          const float* __restrict__ blin)
{
    float bl = blin[0];
    int tid = blockIdx.x * blockDim.x + threadIdx.x;
    int stride = gridDim.x * blockDim.x;
    uint4* ca = (uint4*)(ws + OFF_CA);
    for (int i = tid; i < 65536; i += stride) ca[i] = make_uint4(0u, 0u, 0u, 0u);
    float* xf = (float*)(ws + OFF_XF);
    for (int i = tid; i < (FUT + 1) * BATCH; i += stride) xf[i] = bl;
    unsigned* bar = (unsigned*)(ws + OFF_BAR);
    for (int i = tid; i < NGRP * 64; i += stride) bar[i] = 0u;
    for (int i = tid; i < BATCH * NSTEP; i += stride) out[i] = bl;
}

__global__ void lstm_pack(char* __restrict__ ws,
    const float* __restrict__ Wih0, const float* __restrict__ Whh0,
    const float* __restrict__ bih0, const float* __restrict__ bhh0,
    const float* __restrict__ Wih1, const float* __restrict__ Whh1,
    const float* __restrict__ bih1, const float* __restrict__ bhh1)
{
    int tid = blockIdx.x * blockDim.x + threadIdx.x;
    int stride = gridDim.x * blockDim.x;

    __hip_bfloat16* W0p = (__hip_bfloat16*)(ws + OFF_W0);
    for (int i = tid; i < 32 * 64 * 512; i += stride) {
        int k = i & 511, r = (i >> 9) & 63, m = i >> 15;
        int row = (r >> 4) * HID + m * UPW + (r & 15);
        W0p[i] = __float2bfloat16(Whh0[(size_t)row * HID + k]);
    }
    __hip_bfloat16* W1p = (__hip_bfloat16*)(ws + OFF_W1);
    for (int i = tid; i < 32 * 64 * 1024; i += stride) {
        int k = i & 1023, r = (i >> 10) & 63, m = i >> 16;
        int row = (r >> 4) * HID + m * UPW + (r & 15);
        float v = (k < 512) ? Wih1[(size_t)row * HID + k] : Whh1[(size_t)row * HID + (k - 512)];
        W1p[i] = __float2bfloat16(v);
    }
    float* wi = (float*)(ws + OFF_WI);
    float* b0 = (float*)(ws + OFF_B0);
    float* b1 = (float*)(ws + OFF_B1);
    for (int i = tid; i < 32 * 64; i += stride) {
        int r = i & 63, m = i >> 6;
        int row = (r >> 4) * HID + m * UPW + (r & 15);
        wi[i] = Wih0[row];                  // IN = 1
        b0[i] = bih0[row] + bhh0[row];
        b1[i] = bih1[row] + bhh1[row];
    }
}

__global__ __launch_bounds__(256, 1) void lstm_persist(
    const float* __restrict__ x, const float* __restrict__ wlin,
    float* __restrict__ out, char* __restrict__ ws)
{
    const int tid  = threadIdx.x;
    const int lane = tid & 63;
    const int wave = tid >> 6;
    const int g    = blockIdx.x & 7;   // group -> XCD swizzle
    const int m    = blockIdx.x >> 3;  // member within group: unit slice
    const int bbase = g * BPG;

    __shared__ float gatesS[32][68];
    __shared__ float c0S[32][16];
    __shared__ float c1S[32][16];
    for (int i = tid; i < 32 * 16; i += 256) { c0S[i >> 4][i & 15] = 0.f; c1S[i >> 4][i & 15] = 0.f; }

    const float* wis = (const float*)(ws + OFF_WI) + m * NR;
    const float* b0s = (const float*)(ws + OFF_B0) + m * NR;
    const float* b1s = (const float*)(ws + OFF_B1) + m * NR;
    __hip_bfloat16* CAbase = (__hip_bfloat16*)(ws + OFF_CA) + (size_t)g * 2 * 32 * 1024;
    float* xfeed = (float*)(ws + OFF_XF);
    unsigned* bar = (unsigned*)(ws + OFF_BAR) + g * 64;

    const int fl = lane & 15;          // n / m sub-index in fragment
    const int fq = lane >> 4;          // quad (k sub-chunk)
    const int w  = wave;               // wave = gate tile (ntile), 0..3
    const float wl0 = wlin[m * UPW + (tid & 15)];

    // ---- load this wave's weight slice into registers (192 VGPRs/lane) ----
    const bf16x8* W0row = (const bf16x8*)(ws + OFF_W0 + (size_t)m * NR * 512 * 2)
                          + (size_t)(w * 16 + fl) * 64;
    const bf16x8* W1row = (const bf16x8*)(ws + OFF_W1 + (size_t)m * NR * 1024 * 2)
                          + (size_t)(w * 16 + fl) * 128;
    bf16x8 w0f[16], w1f[32];
#pragma unroll
    for (int ks = 0; ks < 16; ++ks) w0f[ks] = W0row[ks * 4 + fq];
#pragma unroll
    for (int ks = 0; ks < 32; ++ks) w1f[ks] = W1row[ks * 4 + fq];

    unsigned phase = 0;
    for (int t = 0; t < NSTEP; ++t) {
        const int p = t & 1;
        __hip_bfloat16* CAw = CAbase + p * (32 * 1024);
        const __hip_bfloat16* CAr = CAbase + (1 - p) * (32 * 1024);
        const bf16x8* A0 = (const bf16x8*)CAw;   // parity p   (h0 new)
        const bf16x8* A1 = (const bf16x8*)CAr;   // parity 1-p (h0 prev / h1 prev)

        // ---------------- layer 0 GEMM: gates[b][r] = sum_k h0prev[b][k] * W0[r][k]
        f32x4 acc0 = {0.f, 0.f, 0.f, 0.f}, acc1 = {0.f, 0.f, 0.f, 0.f};
#pragma unroll
        for (int ks = 0; ks < 16; ++ks) {
            bf16x8 a0 = A1[fl * 128 + ks * 4 + fq];          // batch rows 0..15
            bf16x8 a1 = A1[(16 + fl) * 128 + ks * 4 + fq];   // batch rows 16..31
            acc0 = __builtin_amdgcn_mfma_f32_16x16x32_bf16(a0, w0f[ks], acc0, 0, 0, 0);
            acc1 = __builtin_amdgcn_mfma_f32_16x16x32_bf16(a1, w0f[ks], acc1, 0, 0, 0);
        }
#pragma unroll
        for (int i = 0; i < 4; ++i) {   // C layout: m = quad*4+reg, n = lane&15
            gatesS[fq * 4 + i][w * 16 + fl]      = acc0[i];
            gatesS[16 + fq * 4 + i][w * 16 + fl] = acc1[i];
        }
        __syncthreads();

        // ---------------- layer 0 elementwise (fp32 state)
#pragma unroll
        for (int pp = 0; pp < 2; ++pp) {
            int b = (tid >> 4) + pp * 16;
            int us = tid & 15;
            float xv = (t < TLEN) ? x[(size_t)(bbase + b) * TLEN + t]
                                  : xfeed[(t - TLEN) * BATCH + bbase + b];
            float gi = gatesS[b][us]      + b0s[us]      + xv * wis[us];
            float gf = gatesS[b][16 + us] + b0s[16 + us] + xv * wis[16 + us];
            float gg = gatesS[b][32 + us] + b0s[32 + us] + xv * wis[32 + us];
            float go = gatesS[b][48 + us] + b0s[48 + us] + xv * wis[48 + us];
            float c = sigf(gf) * c0S[b][us] + sigf(gi) * tanh_fast(gg);
            c0S[b][us] = c;
            float h = sigf(go) * tanh_fast(c);
            CAw[b * 1024 + m * UPW + us] = __float2bfloat16(h);
        }
        __threadfence();
        ++phase;
        group_barrier(bar, phase);   // orders h0 publish -> layer1 reads

        // ---------------- layer 1 GEMM: K = 1024 over [h0_new | h1_prev]
        acc0 = (f32x4){0.f, 0.f, 0.f, 0.f};
        acc1 = (f32x4){0.f, 0.f, 0.f, 0.f};
#pragma unroll
        for (int ks = 0; ks < 32; ++ks) {
            const bf16x8* Asrc = (ks < 16) ? A0 : A1;   // h0_new | h1_prev
            bf16x8 a0 = Asrc[fl * 128 + ks * 4 + fq];
            bf16x8 a1 = Asrc[(16 + fl) * 128 + ks * 4 + fq];
            acc0 = __builtin_amdgcn_mfma_f32_16x16x32_bf16(a0, w1f[ks], acc0, 0, 0, 0);
            acc1 = __builtin_amdgcn_mfma_f32_16x16x32_bf16(a1, w1f[ks], acc1, 0, 0, 0);
        }
#pragma unroll
        for (int i = 0; i < 4; ++i) {
            gatesS[fq * 4 + i][w * 16 + fl]      = acc0[i];
            gatesS[16 + fq * 4 + i][w * 16 + fl] = acc1[i];
        }
        __syncthreads();

        // ---------------- layer 1 elementwise + OUT=1 linear
#pragma unroll
        for (int pp = 0; pp < 2; ++pp) {
            int b = (tid >> 4) + pp * 16;
            int us = tid & 15;
            float gi = gatesS[b][us]      + b1s[us];
            float gf = gatesS[b][16 + us] + b1s[16 + us];
            float gg = gatesS[b][32 + us] + b1s[32 + us];
            float go = gatesS[b][48 + us] + b1s[48 + us];
            float c = sigf(gf) * c1S[b][us] + sigf(gi) * tanh_fast(gg);
            c1S[b][us] = c;
            float h = sigf(go) * tanh_fast(c);
            CAw[b * 1024 + 512 + m * UPW + us] = __float2bfloat16(h);
            float po = wl0 * h;
#pragma unroll
            for (int off = 1; off < 16; off <<= 1) po += __shfl_xor(po, off, 64);
            if ((lane & 15) == 0) {
                atomicAdd(&out[(size_t)(bbase + b) * NSTEP + t], po);
                if (t >= TLEN - 1)
                    atomicAdd(&xfeed[(t - (TLEN - 1)) * BATCH + bbase + b], po);
            }
        }
        // 2nd barrier only needed to order xfeed publish -> next step's read
        if (t >= TLEN - 1) {
            __threadfence();
            ++phase;
            group_barrier(bar, phase);
        } else {
            __syncthreads();   // gatesS reuse within WG
        }
    }
}

extern "C" void kernel_launch(void* const* d_in, const int* in_sizes, int n_in,
                              void* d_out, int out_size, void* d_ws, size_t ws_size,
                              hipStream_t stream)
{
    const float* x    = (const float*)d_in[0];
    const float* Wih0 = (const float*)d_in[1];
    const float* Whh0 = (const float*)d_in[2];
    const float* bih0 = (const float*)d_in[3];
    const float* bhh0 = (const float*)d_in[4];
    const float* Wih1 = (const float*)d_in[5];
    const float* Whh1 = (const float*)d_in[6];
    const float* bih1 = (const float*)d_in[7];
    const float* bhh1 = (const float*)d_in[8];
    const float* Wlin = (const float*)d_in[9];
    const float* blin = (const float*)d_in[10];
    float* out = (float*)d_out;
    char* ws = (char*)d_ws;

    hipLaunchKernelGGL(lstm_init, dim3(256), dim3(256), 0, stream, ws, out, blin);
    hipLaunchKernelGGL(lstm_pack, dim3(512), dim3(256), 0, stream,
                       ws, Wih0, Whh0, bih0, bhh0, Wih1, Whh1, bih1, bhh1);
    hipLaunchKernelGGL(lstm_persist, dim3(256), dim3(256), 0, stream, x, Wlin, out, ws);
}

// Round 3
// 7200.819 us; speedup vs baseline: 5.8722x; 3.2117x over previous
//
#include <hip/hip_runtime.h>
#include <hip/hip_bf16.h>
#include <math.h>

#define HID    512
#define BATCH  256
#define TLEN   512
#define FUT    16
#define NSTEP  (TLEN + FUT)   // 528
#define NGRP   8              // batch groups
#define WPG    32             // workgroups per group
#define BPG    32             // batch per group
#define UPW    16             // hidden units per WG
#define NR     64             // gate rows per WG (4 gates * UPW)
#define ROWP   1032           // padded LDS A-row stride (bf16 elems): +16B pad -> 2-way banks (free)

// workspace byte offsets (all 256-aligned)
#define OFF_W0   0u           // packed Whh0 slices  [32][64][512]  bf16 = 2 MB
#define OFF_W1   2097152u     // packed [Wih1|Whh1]  [32][64][1024] bf16 = 4 MB
#define OFF_CA   6291456u     // activations [grp][2][32][1024] bf16 = 1 MB
#define OFF_XF   7340032u     // feedback outs [FUT+1][256] f32
#define OFF_WI   7357440u     // Wih0 col packed [32][64] f32
#define OFF_B0   7365632u     // bih0+bhh0 packed [32][64] f32
#define OFF_B1   7373824u     // bih1+bhh1 packed [32][64] f32
#define OFF_BAR  7382016u     // 8 groups * 64 uints barrier state

typedef __bf16 bf16x8 __attribute__((ext_vector_type(8)));
typedef float  f32x4  __attribute__((ext_vector_type(4)));

__device__ __forceinline__ float sigf(float v)      { return 1.f / (1.f + __expf(-v)); }
__device__ __forceinline__ float tanh_fast(float v) { return 2.f / (1.f + __expf(-2.f * v)) - 1.f; }

// async global->LDS DMA, 16B per lane; lds dest = wave-uniform base + lane*16
__device__ __forceinline__ void gl2lds16(const __hip_bfloat16* g, __hip_bfloat16* l) {
    __builtin_amdgcn_global_load_lds(
        (const __attribute__((address_space(1))) void*)g,
        (__attribute__((address_space(3))) void*)l,
        16, 0, 0);
}

// group barrier: RELAXED spin (no per-poll L2 invalidate), one acquire on exit.
// Arrival acq_rel RMW provides the release of all prior writes (after __syncthreads).
__device__ __forceinline__ void group_barrier(unsigned* bar, unsigned target) {
    __syncthreads();
    if (threadIdx.x == 0) {
        unsigned arr = __hip_atomic_fetch_add(&bar[0], 1u, __ATOMIC_ACQ_REL, __HIP_MEMORY_SCOPE_AGENT);
        if (arr == WPG - 1) {
            __hip_atomic_store(&bar[0], 0u, __ATOMIC_RELAXED, __HIP_MEMORY_SCOPE_AGENT);
            __hip_atomic_fetch_add(&bar[1], 1u, __ATOMIC_RELEASE, __HIP_MEMORY_SCOPE_AGENT);
        } else {
            while (__hip_atomic_load(&bar[1], __ATOMIC_RELAXED, __HIP_MEMORY_SCOPE_AGENT) < target)
                __builtin_amdgcn_s_sleep(1);
            (void)__hip_atomic_load(&bar[1], __ATOMIC_ACQUIRE, __HIP_MEMORY_SCOPE_AGENT);
        }
    }
    __syncthreads();
}

__global__ void lstm_init(char* __restrict__ ws, float* __restrict__ out,
                          const float* __restrict__ blin)
{
    float bl = blin[0];
    int tid = blockIdx.x * blockDim.x + threadIdx.x;
    int stride = gridDim.x * blockDim.x;
    uint4* ca = (uint4*)(ws + OFF_CA);
    for (int i = tid; i < 65536; i += stride) ca[i] = make_uint4(0u, 0u, 0u, 0u);
    float* xf = (float*)(ws + OFF_XF);
    for (int i = tid; i < (FUT + 1) * BATCH; i += stride) xf[i] = bl;
    unsigned* bar = (unsigned*)(ws + OFF_BAR);
    for (int i = tid; i < NGRP * 64; i += stride) bar[i] = 0u;
    for (int i = tid; i < BATCH * NSTEP; i += stride) out[i] = bl;
}

__global__ void lstm_pack(char* __restrict__ ws,
    const float* __restrict__ Wih0, const float* __restrict__ Whh0,
    const float* __restrict__ bih0, const float* __restrict__ bhh0,
    const float* __restrict__ Wih1, const float* __restrict__ Whh1,
    const float* __restrict__ bih1, const float* __restrict__ bhh1)
{
    int tid = blockIdx.x * blockDim.x + threadIdx.x;
    int stride = gridDim.x * blockDim.x;

    __hip_bfloat16* W0p = (__hip_bfloat16*)(ws + OFF_W0);
    for (int i = tid; i < 32 * 64 * 512; i += stride) {
        int k = i & 511, r = (i >> 9) & 63, m = i >> 15;
        int row = (r >> 4) * HID + m * UPW + (r & 15);
        W0p[i] = __float2bfloat16(Whh0[(size_t)row * HID + k]);
    }
    __hip_bfloat16* W1p = (__hip_bfloat16*)(ws + OFF_W1);
    for (int i = tid; i < 32 * 64 * 1024; i += stride) {
        int k = i & 1023, r = (i >> 10) & 63, m = i >> 16;
        int row = (r >> 4) * HID + m * UPW + (r & 15);
        float v = (k < 512) ? Wih1[(size_t)row * HID + k] : Whh1[(size_t)row * HID + (k - 512)];
        W1p[i] = __float2bfloat16(v);
    }
    float* wi = (float*)(ws + OFF_WI);
    float* b0 = (float*)(ws + OFF_B0);
    float* b1 = (float*)(ws + OFF_B1);
    for (int i = tid; i < 32 * 64; i += stride) {
        int r = i & 63, m = i >> 6;
        int row = (r >> 4) * HID + m * UPW + (r & 15);
        wi[i] = Wih0[row];                  // IN = 1
        b0[i] = bih0[row] + bhh0[row];
        b1[i] = bih1[row] + bhh1[row];
    }
}

__global__ __launch_bounds__(256, 1) void lstm_persist(
    const float* __restrict__ x, const float* __restrict__ wlin,
    float* __restrict__ out, char* __restrict__ ws)
{
    const int tid  = threadIdx.x;
    const int lane = tid & 63;
    const int wave = tid >> 6;
    const int g    = blockIdx.x & 7;   // group -> XCD swizzle
    const int m    = blockIdx.x >> 3;  // member within group: unit slice
    const int bbase = g * BPG;

    __shared__ __attribute__((aligned(16))) __hip_bfloat16 As[32 * ROWP]; // staged [h0|h1] rows
    __shared__ float gatesS[32][68];

    // zero As (t=0 reads h0prev=0 from it)
    {
        int* az = (int*)As;
        for (int i = tid; i < (32 * ROWP * 2) / 4; i += 256) az[i] = 0;
    }

    const float* wis = (const float*)(ws + OFF_WI) + m * NR;
    const float* b0s = (const float*)(ws + OFF_B0) + m * NR;
    const float* b1s = (const float*)(ws + OFF_B1) + m * NR;
    __hip_bfloat16* CAbase = (__hip_bfloat16*)(ws + OFF_CA) + (size_t)g * 2 * 32 * 1024;
    float* xfeed = (float*)(ws + OFF_XF);
    unsigned* bar = (unsigned*)(ws + OFF_BAR) + g * 64;

    const int fl = lane & 15;          // n sub-index in fragment
    const int fq = lane >> 4;          // quad (k sub-chunk)
    const int w  = wave;               // wave = gate tile, 0..3
    const int us  = tid & 15;          // unit within slice (elementwise)
    const int b0r = tid >> 4;          // batch row 0..15
    const int b1r = b0r + 16;

    // per-thread constants in registers
    const float wl0 = wlin[m * UPW + us];
    float wiR[4], b0R[4], b1R[4];
#pragma unroll
    for (int q = 0; q < 4; ++q) {
        wiR[q] = wis[q * 16 + us];
        b0R[q] = b0s[q * 16 + us];
        b1R[q] = b1s[q * 16 + us];
    }
    float c00 = 0.f, c01 = 0.f, c10 = 0.f, c11 = 0.f;  // cell state regs [layer][half]

    // ---- load this wave's weight slice into registers (192 VGPRs/lane) ----
    const bf16x8* W0row = (const bf16x8*)(ws + OFF_W0 + (size_t)m * NR * 512 * 2)
                          + (size_t)(w * 16 + fl) * 64;
    const bf16x8* W1row = (const bf16x8*)(ws + OFF_W1 + (size_t)m * NR * 1024 * 2)
                          + (size_t)(w * 16 + fl) * 128;
    bf16x8 w0f[16], w1f[32];
#pragma unroll
    for (int ks = 0; ks < 16; ++ks) w0f[ks] = W0row[ks * 4 + fq];
#pragma unroll
    for (int ks = 0; ks < 32; ++ks) w1f[ks] = W1row[ks * 4 + fq];

    __syncthreads();  // As zeroed before use

    unsigned phase = 0;
    for (int t = 0; t < NSTEP; ++t) {
        const int p = t & 1;
        __hip_bfloat16* CAw = CAbase + p * (32 * 1024);
        const __hip_bfloat16* CAr = CAbase + (1 - p) * (32 * 1024);

        // prefetch x / feedback early (overlaps L0 GEMM)
        float xv0, xv1;
        if (t < TLEN) {
            xv0 = x[(size_t)(bbase + b0r) * TLEN + t];
            xv1 = x[(size_t)(bbase + b1r) * TLEN + t];
        } else {
            xv0 = xfeed[(t - TLEN) * BATCH + bbase + b0r];
            xv1 = xfeed[(t - TLEN) * BATCH + bbase + b1r];
        }

        // ---------------- layer 0 GEMM from LDS (h0prev in As cols [0,512))
        f32x4 acc0 = {0.f, 0.f, 0.f, 0.f}, acc1 = {0.f, 0.f, 0.f, 0.f};
        {
            const bf16x8* a0p = (const bf16x8*)&As[(size_t)fl * ROWP];
            const bf16x8* a1p = (const bf16x8*)&As[(size_t)(16 + fl) * ROWP];
#pragma unroll
            for (int ks = 0; ks < 16; ++ks) {
                bf16x8 a0 = a0p[ks * 4 + fq];
                bf16x8 a1 = a1p[ks * 4 + fq];
                acc0 = __builtin_amdgcn_mfma_f32_16x16x32_bf16(a0, w0f[ks], acc0, 0, 0, 0);
                acc1 = __builtin_amdgcn_mfma_f32_16x16x32_bf16(a1, w0f[ks], acc1, 0, 0, 0);
            }
        }
#pragma unroll
        for (int i = 0; i < 4; ++i) {   // C layout: m = quad*4+reg, n = lane&15
            gatesS[fq * 4 + i][w * 16 + fl]      = acc0[i];
            gatesS[16 + fq * 4 + i][w * 16 + fl] = acc1[i];
        }
        __syncthreads();

        // ---------------- layer 0 elementwise (state in regs)
        {
            float gi = gatesS[b0r][us]      + b0R[0] + xv0 * wiR[0];
            float gf = gatesS[b0r][16 + us] + b0R[1] + xv0 * wiR[1];
            float gg = gatesS[b0r][32 + us] + b0R[2] + xv0 * wiR[2];
            float go = gatesS[b0r][48 + us] + b0R[3] + xv0 * wiR[3];
            c00 = sigf(gf) * c00 + sigf(gi) * tanh_fast(gg);
            CAw[b0r * 1024 + m * UPW + us] = __float2bfloat16(sigf(go) * tanh_fast(c00));
        }
        {
            float gi = gatesS[b1r][us]      + b0R[0] + xv1 * wiR[0];
            float gf = gatesS[b1r][16 + us] + b0R[1] + xv1 * wiR[1];
            float gg = gatesS[b1r][32 + us] + b0R[2] + xv1 * wiR[2];
            float go = gatesS[b1r][48 + us] + b0R[3] + xv1 * wiR[3];
            c01 = sigf(gf) * c01 + sigf(gi) * tanh_fast(gg);
            CAw[b1r * 1024 + m * UPW + us] = __float2bfloat16(sigf(go) * tanh_fast(c01));
        }

        ++phase;
        group_barrier(bar, phase);   // releases h0 publish, acquires all WGs' h0

        // ---------------- stage [h0new | h1prev] -> LDS As (64 x 1KB chunks, 16/wave)
        {
#pragma unroll
            for (int ci = 0; ci < 16; ++ci) {
                int c = wave * 16 + ci;
                int b = c >> 1, half = c & 1;
                const __hip_bfloat16* gsrc =
                    (half ? (CAr + b * 1024 + 512) : (CAw + b * 1024)) + lane * 8;
                gl2lds16(gsrc, &As[b * ROWP + half * 512]);
            }
            __builtin_amdgcn_s_waitcnt(0);
            __syncthreads();
        }

        // ---------------- layer 1 GEMM: K=1024 over staged [h0new | h1prev]
        acc0 = (f32x4){0.f, 0.f, 0.f, 0.f};
        acc1 = (f32x4){0.f, 0.f, 0.f, 0.f};
        {
            const bf16x8* a0p = (const bf16x8*)&As[(size_t)fl * ROWP];
            const bf16x8* a1p = (const bf16x8*)&As[(size_t)(16 + fl) * ROWP];
#pragma unroll
            for (int ks = 0; ks < 32; ++ks) {
                bf16x8 a0 = a0p[ks * 4 + fq];
                bf16x8 a1 = a1p[ks * 4 + fq];
                acc0 = __builtin_amdgcn_mfma_f32_16x16x32_bf16(a0, w1f[ks], acc0, 0, 0, 0);
                acc1 = __builtin_amdgcn_mfma_f32_16x16x32_bf16(a1, w1f[ks], acc1, 0, 0, 0);
            }
        }
#pragma unroll
        for (int i = 0; i < 4; ++i) {
            gatesS[fq * 4 + i][w * 16 + fl]      = acc0[i];
            gatesS[16 + fq * 4 + i][w * 16 + fl] = acc1[i];
        }
        __syncthreads();

        // ---------------- layer 1 elementwise + OUT=1 linear
        {
            float gi = gatesS[b0r][us]      + b1R[0];
            float gf = gatesS[b0r][16 + us] + b1R[1];
            float gg = gatesS[b0r][32 + us] + b1R[2];
            float go = gatesS[b0r][48 + us] + b1R[3];
            c10 = sigf(gf) * c10 + sigf(gi) * tanh_fast(gg);
            float h = sigf(go) * tanh_fast(c10);
            CAw[b0r * 1024 + 512 + m * UPW + us] = __float2bfloat16(h);
            float po = wl0 * h;
#pragma unroll
            for (int off = 1; off < 16; off <<= 1) po += __shfl_xor(po, off, 64);
            if (us == 0) {
                atomicAdd(&out[(size_t)(bbase + b0r) * NSTEP + t], po);
                if (t >= TLEN - 1)
                    atomicAdd(&xfeed[(t - (TLEN - 1)) * BATCH + bbase + b0r], po);
            }
        }
        {
            float gi = gatesS[b1r][us]      + b1R[0];
            float gf = gatesS[b1r][16 + us] + b1R[1];
            float gg = gatesS[b1r][32 + us] + b1R[2];
            float go = gatesS[b1r][48 + us] + b1R[3];
            c11 = sigf(gf) * c11 + sigf(gi) * tanh_fast(gg);
            float h = sigf(go) * tanh_fast(c11);
            CAw[b1r * 1024 + 512 + m * UPW + us] = __float2bfloat16(h);
            float po = wl0 * h;
#pragma unroll
            for (int off = 1; off < 16; off <<= 1) po += __shfl_xor(po, off, 64);
            if (us == 0) {
                atomicAdd(&out[(size_t)(bbase + b1r) * NSTEP + t], po);
                if (t >= TLEN - 1)
                    atomicAdd(&xfeed[(t - (TLEN - 1)) * BATCH + bbase + b1r], po);
            }
        }

        // 2nd barrier only needed to order xfeed publish -> next step's read
        if (t >= TLEN - 1) {
            ++phase;
            group_barrier(bar, phase);
        } else {
            __syncthreads();   // gatesS reuse guard within WG
        }
    }
}

extern "C" void kernel_launch(void* const* d_in, const int* in_sizes, int n_in,
                              void* d_out, int out_size, void* d_ws, size_t ws_size,
                              hipStream_t stream)
{
    const float* x    = (const float*)d_in[0];
    const float* Wih0 = (const float*)d_in[1];
    const float* Whh0 = (const float*)d_in[2];
    const float* bih0 = (const float*)d_in[3];
    const float* bhh0 = (const float*)d_in[4];
    const float* Wih1 = (const float*)d_in[5];
    const float* Whh1 = (const float*)d_in[6];
    const float* bih1 = (const float*)d_in[7];
    const float* bhh1 = (const float*)d_in[8];
    const float* Wlin = (const float*)d_in[9];
    const float* blin = (const float*)d_in[10];
    float* out = (float*)d_out;
    char* ws = (char*)d_ws;

    hipLaunchKernelGGL(lstm_init, dim3(256), dim3(256), 0, stream, ws, out, blin);
    hipLaunchKernelGGL(lstm_pack, dim3(512), dim3(256), 0, stream,
                       ws, Wih0, Whh0, bih0, bhh0, Wih1, Whh1, bih1, bhh1);
    hipLaunchKernelGGL(lstm_persist, dim3(256), dim3(256), 0, stream, x, Wlin, out, ws);
}

// Round 4
// 6364.986 us; speedup vs baseline: 6.6434x; 1.1313x over previous
//
#include <hip/hip_runtime.h>
#include <hip/hip_bf16.h>
#include <math.h>

#define HID    512
#define BATCH  256
#define TLEN   512
#define FUT    16
#define NSTEP  (TLEN + FUT)   // 528
#define NGRP   8              // batch groups
#define WPG    32             // workgroups per group
#define BPG    32             // batch per group
#define UPW    16             // hidden units per WG
#define NR     64             // gate rows per WG (4 gates * UPW)
#define ROWP   1032           // padded LDS A-row stride (bf16 elems)

// workspace byte offsets (all 256-aligned)
#define OFF_W0   0u           // packed Whh0 slices  [32][64][512]  bf16 = 2 MB
#define OFF_W1   2097152u     // packed [Wih1|Whh1]  [32][64][1024] bf16 = 4 MB
#define OFF_CA   6291456u     // activations [grp][2][32][1024] bf16 = 1 MB
#define OFF_XF   7340032u     // feedback outs [FUT+1][256] f32
#define OFF_WI   7357440u     // Wih0 col packed [32][64] f32
#define OFF_B0   7365632u     // bih0+bhh0 packed [32][64] f32
#define OFF_B1   7373824u     // bih1+bhh1 packed [32][64] f32
#define OFF_BAR  7382016u     // 8 groups * 64 uints flag state (256B/group)
#define OFF_XT   7384064u     // x transposed [TLEN][BATCH] f32 = 512 KB

typedef __bf16 bf16x8 __attribute__((ext_vector_type(8)));
typedef float  f32x4  __attribute__((ext_vector_type(4)));

__device__ __forceinline__ float sigf(float v)      { return 1.f / (1.f + __expf(-v)); }
__device__ __forceinline__ float tanh_fast(float v) { return 2.f / (1.f + __expf(-2.f * v)) - 1.f; }

// async global->LDS DMA, 16B per lane; lds dest = wave-uniform base + lane*16
__device__ __forceinline__ void gl2lds16(const __hip_bfloat16* g, __hip_bfloat16* l) {
    __builtin_amdgcn_global_load_lds(
        (const __attribute__((address_space(1))) void*)g,
        (__attribute__((address_space(3))) void*)l,
        16, 0, 0);
}

// Flag-array group barrier: per-WG release store to its OWN slot (no RMW
// serialization), wave0 polls all WPG flags lane-parallel + acquire fence.
__device__ __forceinline__ void flag_barrier(unsigned* flags, int m, unsigned phase) {
    __syncthreads();
    if (threadIdx.x == 0)
        __hip_atomic_store(&flags[m], phase, __ATOMIC_RELEASE, __HIP_MEMORY_SCOPE_AGENT);
    if (threadIdx.x < 64) {
        const int lane = threadIdx.x;
        for (;;) {
            unsigned f = phase;
            if (lane < WPG)
                f = __hip_atomic_load(&flags[lane], __ATOMIC_RELAXED, __HIP_MEMORY_SCOPE_AGENT);
            if (__ballot(f >= phase) == ~0ull) break;
            __builtin_amdgcn_s_sleep(1);
        }
        __builtin_amdgcn_fence(__ATOMIC_ACQUIRE, "agent");
    }
    __syncthreads();
}

__global__ void lstm_init(char* __restrict__ ws, float* __restrict__ out,
                          const float* __restrict__ blin)
{
    float bl = blin[0];
    int tid = blockIdx.x * blockDim.x + threadIdx.x;
    int stride = gridDim.x * blockDim.x;
    uint4* ca = (uint4*)(ws + OFF_CA);
    for (int i = tid; i < 65536; i += stride) ca[i] = make_uint4(0u, 0u, 0u, 0u);
    float* xf = (float*)(ws + OFF_XF);
    for (int i = tid; i < (FUT + 1) * BATCH; i += stride) xf[i] = bl;
    unsigned* bar = (unsigned*)(ws + OFF_BAR);
    for (int i = tid; i < NGRP * 64; i += stride) bar[i] = 0u;
    for (int i = tid; i < BATCH * NSTEP; i += stride) out[i] = bl;
}

__global__ void lstm_pack(char* __restrict__ ws,
    const float* __restrict__ x,
    const float* __restrict__ Wih0, const float* __restrict__ Whh0,
    const float* __restrict__ bih0, const float* __restrict__ bhh0,
    const float* __restrict__ Wih1, const float* __restrict__ Whh1,
    const float* __restrict__ bih1, const float* __restrict__ bhh1)
{
    int tid = blockIdx.x * blockDim.x + threadIdx.x;
    int stride = gridDim.x * blockDim.x;

    __hip_bfloat16* W0p = (__hip_bfloat16*)(ws + OFF_W0);
    for (int i = tid; i < 32 * 64 * 512; i += stride) {
        int k = i & 511, r = (i >> 9) & 63, m = i >> 15;
        int row = (r >> 4) * HID + m * UPW + (r & 15);
        W0p[i] = __float2bfloat16(Whh0[(size_t)row * HID + k]);
    }
    __hip_bfloat16* W1p = (__hip_bfloat16*)(ws + OFF_W1);
    for (int i = tid; i < 32 * 64 * 1024; i += stride) {
        int k = i & 1023, r = (i >> 10) & 63, m = i >> 16;
        int row = (r >> 4) * HID + m * UPW + (r & 15);
        float v = (k < 512) ? Wih1[(size_t)row * HID + k] : Whh1[(size_t)row * HID + (k - 512)];
        W1p[i] = __float2bfloat16(v);
    }
    float* wi = (float*)(ws + OFF_WI);
    float* b0 = (float*)(ws + OFF_B0);
    float* b1 = (float*)(ws + OFF_B1);
    for (int i = tid; i < 32 * 64; i += stride) {
        int r = i & 63, m = i >> 6;
        int row = (r >> 4) * HID + m * UPW + (r & 15);
        wi[i] = Wih0[row];                  // IN = 1
        b0[i] = bih0[row] + bhh0[row];
        b1[i] = bih1[row] + bhh1[row];
    }
    float* xT = (float*)(ws + OFF_XT);      // [T][B] for coalesced step reads
    for (int i = tid; i < TLEN * BATCH; i += stride) {
        int t = i >> 8, b = i & 255;
        xT[i] = x[(size_t)b * TLEN + t];
    }
}

__global__ __launch_bounds__(256, 1) void lstm_persist(
    const float* __restrict__ wlin,
    float* __restrict__ out, char* __restrict__ ws)
{
    const int tid  = threadIdx.x;
    const int lane = tid & 63;
    const int wave = tid >> 6;
    const int g    = blockIdx.x & 7;   // group -> XCD swizzle
    const int m    = blockIdx.x >> 3;  // member within group: unit slice
    const int bbase = g * BPG;

    __shared__ __attribute__((aligned(16))) __hip_bfloat16 As[32 * ROWP]; // staged [h0|h1] rows
    __shared__ float gatesS[32][68];

    // zero As (t=0 reads h0prev=0 from it)
    {
        int* az = (int*)As;
        for (int i = tid; i < (32 * ROWP * 2) / 4; i += 256) az[i] = 0;
    }

    const float* wis = (const float*)(ws + OFF_WI) + m * NR;
    const float* b0s = (const float*)(ws + OFF_B0) + m * NR;
    const float* b1s = (const float*)(ws + OFF_B1) + m * NR;
    __hip_bfloat16* CAbase = (__hip_bfloat16*)(ws + OFF_CA) + (size_t)g * 2 * 32 * 1024;
    float* xfeed = (float*)(ws + OFF_XF);
    const float* xT = (const float*)(ws + OFF_XT);
    unsigned* flags = (unsigned*)(ws + OFF_BAR) + g * 64;

    const int fl = lane & 15;          // n sub-index in fragment
    const int fq = lane >> 4;          // quad (k sub-chunk)
    const int w  = wave;               // wave = gate tile, 0..3
    const int us  = tid & 15;          // unit within slice (elementwise)
    const int b0r = tid >> 4;          // batch row 0..15
    const int b1r = b0r + 16;

    // per-thread constants in registers
    const float wl0 = wlin[m * UPW + us];
    float wiR[4], b0R[4], b1R[4];
#pragma unroll
    for (int q = 0; q < 4; ++q) {
        wiR[q] = wis[q * 16 + us];
        b0R[q] = b0s[q * 16 + us];
        b1R[q] = b1s[q * 16 + us];
    }
    float c00 = 0.f, c01 = 0.f, c10 = 0.f, c11 = 0.f;  // cell state regs

    // ---- load this wave's weight slice into registers (192 VGPRs/lane) ----
    const bf16x8* W0row = (const bf16x8*)(ws + OFF_W0 + (size_t)m * NR * 512 * 2)
                          + (size_t)(w * 16 + fl) * 64;
    const bf16x8* W1row = (const bf16x8*)(ws + OFF_W1 + (size_t)m * NR * 1024 * 2)
                          + (size_t)(w * 16 + fl) * 128;
    bf16x8 w0f[16], w1f[32];
#pragma unroll
    for (int ks = 0; ks < 16; ++ks) w0f[ks] = W0row[ks * 4 + fq];
#pragma unroll
    for (int ks = 0; ks < 32; ++ks) w1f[ks] = W1row[ks * 4 + fq];

    __syncthreads();  // As zeroed before use

    unsigned phase = 0;
    for (int t = 0; t < NSTEP; ++t) {
        const int p = t & 1;
        __hip_bfloat16* CAw = CAbase + p * (32 * 1024);
        const __hip_bfloat16* CAr = CAbase + (1 - p) * (32 * 1024);

        // prefetch x / feedback early (coalesced via xT; overlaps L0 GEMM)
        float xv0, xv1;
        if (t < TLEN) {
            xv0 = xT[t * BATCH + bbase + b0r];
            xv1 = xT[t * BATCH + bbase + b1r];
        } else {
            xv0 = xfeed[(t - TLEN) * BATCH + bbase + b0r];
            xv1 = xfeed[(t - TLEN) * BATCH + bbase + b1r];
        }

        // ---------------- layer 0 GEMM from LDS (h0prev in As cols [0,512))
        f32x4 acc0 = {0.f, 0.f, 0.f, 0.f}, acc1 = {0.f, 0.f, 0.f, 0.f};
        {
            const bf16x8* a0p = (const bf16x8*)&As[(size_t)fl * ROWP];
            const bf16x8* a1p = (const bf16x8*)&As[(size_t)(16 + fl) * ROWP];
#pragma unroll
            for (int ks = 0; ks < 16; ++ks) {
                bf16x8 a0 = a0p[ks * 4 + fq];
                bf16x8 a1 = a1p[ks * 4 + fq];
                acc0 = __builtin_amdgcn_mfma_f32_16x16x32_bf16(a0, w0f[ks], acc0, 0, 0, 0);
                acc1 = __builtin_amdgcn_mfma_f32_16x16x32_bf16(a1, w0f[ks], acc1, 0, 0, 0);
            }
        }
#pragma unroll
        for (int i = 0; i < 4; ++i) {   // C layout: m = quad*4+reg, n = lane&15
            gatesS[fq * 4 + i][w * 16 + fl]      = acc0[i];
            gatesS[16 + fq * 4 + i][w * 16 + fl] = acc1[i];
        }
        __syncthreads();

        // ---------------- layer 0 elementwise (state in regs)
        {
            float gi = gatesS[b0r][us]      + b0R[0] + xv0 * wiR[0];
            float gf = gatesS[b0r][16 + us] + b0R[1] + xv0 * wiR[1];
            float gg = gatesS[b0r][32 + us] + b0R[2] + xv0 * wiR[2];
            float go = gatesS[b0r][48 + us] + b0R[3] + xv0 * wiR[3];
            c00 = sigf(gf) * c00 + sigf(gi) * tanh_fast(gg);
            CAw[b0r * 1024 + m * UPW + us] = __float2bfloat16(sigf(go) * tanh_fast(c00));
        }
        {
            float gi = gatesS[b1r][us]      + b0R[0] + xv1 * wiR[0];
            float gf = gatesS[b1r][16 + us] + b0R[1] + xv1 * wiR[1];
            float gg = gatesS[b1r][32 + us] + b0R[2] + xv1 * wiR[2];
            float go = gatesS[b1r][48 + us] + b0R[3] + xv1 * wiR[3];
            c01 = sigf(gf) * c01 + sigf(gi) * tanh_fast(gg);
            CAw[b1r * 1024 + m * UPW + us] = __float2bfloat16(sigf(go) * tanh_fast(c01));
        }

        ++phase;
        flag_barrier(flags, m, phase);   // h0 publish -> all WGs

        // ---------------- stage [h0new | h1prev] -> LDS As (64 x 1KB chunks, 16/wave)
        {
#pragma unroll
            for (int ci = 0; ci < 16; ++ci) {
                int c = wave * 16 + ci;
                int b = c >> 1, half = c & 1;
                const __hip_bfloat16* gsrc =
                    (half ? (CAr + b * 1024 + 512) : (CAw + b * 1024)) + lane * 8;
                gl2lds16(gsrc, &As[b * ROWP + half * 512]);
            }
            __builtin_amdgcn_s_waitcnt(0);
            __syncthreads();
        }

        // ---------------- layer 1 GEMM: K=1024 over staged [h0new | h1prev]
        acc0 = (f32x4){0.f, 0.f, 0.f, 0.f};
        acc1 = (f32x4){0.f, 0.f, 0.f, 0.f};
        {
            const bf16x8* a0p = (const bf16x8*)&As[(size_t)fl * ROWP];
            const bf16x8* a1p = (const bf16x8*)&As[(size_t)(16 + fl) * ROWP];
#pragma unroll
            for (int ks = 0; ks < 32; ++ks) {
                bf16x8 a0 = a0p[ks * 4 + fq];
                bf16x8 a1 = a1p[ks * 4 + fq];
                acc0 = __builtin_amdgcn_mfma_f32_16x16x32_bf16(a0, w1f[ks], acc0, 0, 0, 0);
                acc1 = __builtin_amdgcn_mfma_f32_16x16x32_bf16(a1, w1f[ks], acc1, 0, 0, 0);
            }
        }
#pragma unroll
        for (int i = 0; i < 4; ++i) {
            gatesS[fq * 4 + i][w * 16 + fl]      = acc0[i];
            gatesS[16 + fq * 4 + i][w * 16 + fl] = acc1[i];
        }
        __syncthreads();

        // ---------------- layer 1 elementwise + OUT=1 linear
        {
            float gi = gatesS[b0r][us]      + b1R[0];
            float gf = gatesS[b0r][16 + us] + b1R[1];
            float gg = gatesS[b0r][32 + us] + b1R[2];
            float go = gatesS[b0r][48 + us] + b1R[3];
            c10 = sigf(gf) * c10 + sigf(gi) * tanh_fast(gg);
            float h = sigf(go) * tanh_fast(c10);
            CAw[b0r * 1024 + 512 + m * UPW + us] = __float2bfloat16(h);
            float po = wl0 * h;
#pragma unroll
            for (int off = 1; off < 16; off <<= 1) po += __shfl_xor(po, off, 64);
            if (us == 0) {
                atomicAdd(&out[(size_t)(bbase + b0r) * NSTEP + t], po);
                if (t >= TLEN - 1)
                    atomicAdd(&xfeed[(t - (TLEN - 1)) * BATCH + bbase + b0r], po);
            }
        }
        {
            float gi = gatesS[b1r][us]      + b1R[0];
            float gf = gatesS[b1r][16 + us] + b1R[1];
            float gg = gatesS[b1r][32 + us] + b1R[2];
            float go = gatesS[b1r][48 + us] + b1R[3];
            c11 = sigf(gf) * c11 + sigf(gi) * tanh_fast(gg);
            float h = sigf(go) * tanh_fast(c11);
            CAw[b1r * 1024 + 512 + m * UPW + us] = __float2bfloat16(h);
            float po = wl0 * h;
#pragma unroll
            for (int off = 1; off < 16; off <<= 1) po += __shfl_xor(po, off, 64);
            if (us == 0) {
                atomicAdd(&out[(size_t)(bbase + b1r) * NSTEP + t], po);
                if (t >= TLEN - 1)
                    atomicAdd(&xfeed[(t - (TLEN - 1)) * BATCH + bbase + b1r], po);
            }
        }

        // 2nd barrier only needed to order xfeed publish -> next step's read
        if (t >= TLEN - 1) {
            ++phase;
            flag_barrier(flags, m, phase);
        } else {
            __syncthreads();   // gatesS reuse guard within WG
        }
    }
}

extern "C" void kernel_launch(void* const* d_in, const int* in_sizes, int n_in,
                              void* d_out, int out_size, void* d_ws, size_t ws_size,
                              hipStream_t stream)
{
    const float* x    = (const float*)d_in[0];
    const float* Wih0 = (const float*)d_in[1];
    const float* Whh0 = (const float*)d_in[2];
    const float* bih0 = (const float*)d_in[3];
    const float* bhh0 = (const float*)d_in[4];
    const float* Wih1 = (const float*)d_in[5];
    const float* Whh1 = (const float*)d_in[6];
    const float* bih1 = (const float*)d_in[7];
    const float* bhh1 = (const float*)d_in[8];
    const float* Wlin = (const float*)d_in[9];
    const float* blin = (const float*)d_in[10];
    float* out = (float*)d_out;
    char* ws = (char*)d_ws;

    hipLaunchKernelGGL(lstm_init, dim3(256), dim3(256), 0, stream, ws, out, blin);
    hipLaunchKernelGGL(lstm_pack, dim3(512), dim3(256), 0, stream,
                       ws, x, Wih0, Whh0, bih0, bhh0, Wih1, Whh1, bih1, bhh1);
    hipLaunchKernelGGL(lstm_persist, dim3(256), dim3(256), 0, stream, Wlin, out, ws);
}

// Round 5
// 3998.218 us; speedup vs baseline: 10.5759x; 1.5920x over previous
//
#include <hip/hip_runtime.h>
#include <hip/hip_bf16.h>
#include <math.h>

#define HID    512
#define BATCH  256
#define TLEN   512
#define FUT    16
#define NSTEP  (TLEN + FUT)   // 528
#define NGRP   8              // batch groups
#define WPG    32             // workgroups per group
#define BPG    32             // batch per group
#define UPW    16             // hidden units per WG
#define NR     64             // gate rows per WG (4 gates * UPW)
#define ROWP   1032           // padded LDS A-row stride (bf16 elems) = 2064 B

// workspace byte offsets (all 256-aligned)
#define OFF_W0   0u           // packed Whh0 slices  [32][64][512]  bf16 = 2 MB
#define OFF_W1   2097152u     // packed [Wih1|Whh1]  [32][64][1024] bf16 = 4 MB
#define OFF_CA   6291456u     // activations [grp][p][half][m][b][us] bf16 = 8*128KB = 1 MB
#define OFF_XF   7340032u     // feedback outs [FUT+1][256] f32
#define OFF_WI   7357440u     // Wih0 col packed [32][64] f32
#define OFF_B0   7365632u     // bih0+bhh0 packed [32][64] f32
#define OFF_B1   7373824u     // bih1+bhh1 packed [32][64] f32
#define OFF_BAR  7382016u     // 8 groups * 64 uints flag state (256B/group)
#define OFF_XT   7384064u     // x transposed [TLEN][BATCH] f32 = 512 KB

typedef __bf16 bf16x8 __attribute__((ext_vector_type(8)));
typedef float  f32x4  __attribute__((ext_vector_type(4)));

__device__ __forceinline__ float sigf(float v)      { return 1.f / (1.f + __expf(-v)); }
__device__ __forceinline__ float tanh_fast(float v) { return 2.f / (1.f + __expf(-2.f * v)) - 1.f; }

// write-through 2B store: bypasses L2 (sc0 sc1) -> coherent at LLC, no wbl2 needed
__device__ __forceinline__ void store_short_llc(void* p, unsigned short v) {
    asm volatile("global_store_short %0, %1, off sc0 sc1"
                 :: "v"(p), "v"((unsigned)v) : "memory");
}

// async global->LDS DMA, 16B/lane, aux=17 = sc0|sc1 (CPol GLC|SCC): read LLC, skip stale L2
__device__ __forceinline__ void gl2lds16_llc(const void* g, void* l) {
    __builtin_amdgcn_global_load_lds(
        (const __attribute__((address_space(1))) void*)g,
        (__attribute__((address_space(3))) void*)l,
        16, 0, 17);
}

// Flag-array group barrier, pure LLC atomics, NO whole-cache ops.
// __syncthreads drains each wave's vmem (incl. sc1 publish stores) before the
// flag store; poll-exit branch orders subsequent loads after flag observation.
__device__ __forceinline__ void flag_barrier(unsigned* flags, int m, unsigned phase) {
    __builtin_amdgcn_s_waitcnt(0);
    __syncthreads();
    if (threadIdx.x == 0)
        __hip_atomic_store(&flags[m], phase, __ATOMIC_RELAXED, __HIP_MEMORY_SCOPE_AGENT);
    if (threadIdx.x < 64) {
        const int lane = threadIdx.x;
        for (;;) {
            unsigned f = phase;
            if (lane < WPG)
                f = __hip_atomic_load(&flags[lane], __ATOMIC_RELAXED, __HIP_MEMORY_SCOPE_AGENT);
            if (__ballot(f >= phase) == ~0ull) break;
            __builtin_amdgcn_s_sleep(1);
        }
    }
    __syncthreads();
}

__global__ void lstm_init(char* __restrict__ ws, float* __restrict__ out,
                          const float* __restrict__ blin)
{
    float bl = blin[0];
    int tid = blockIdx.x * blockDim.x + threadIdx.x;
    int stride = gridDim.x * blockDim.x;
    uint4* ca = (uint4*)(ws + OFF_CA);
    for (int i = tid; i < 65536; i += stride) ca[i] = make_uint4(0u, 0u, 0u, 0u);
    float* xf = (float*)(ws + OFF_XF);
    for (int i = tid; i < (FUT + 1) * BATCH; i += stride) xf[i] = bl;
    unsigned* bar = (unsigned*)(ws + OFF_BAR);
    for (int i = tid; i < NGRP * 64; i += stride) bar[i] = 0u;
    for (int i = tid; i < BATCH * NSTEP; i += stride) out[i] = bl;
}

__global__ void lstm_pack(char* __restrict__ ws,
    const float* __restrict__ x,
    const float* __restrict__ Wih0, const float* __restrict__ Whh0,
    const float* __restrict__ bih0, const float* __restrict__ bhh0,
    const float* __restrict__ Wih1, const float* __restrict__ Whh1,
    const float* __restrict__ bih1, const float* __restrict__ bhh1)
{
    int tid = blockIdx.x * blockDim.x + threadIdx.x;
    int stride = gridDim.x * blockDim.x;

    __hip_bfloat16* W0p = (__hip_bfloat16*)(ws + OFF_W0);
    for (int i = tid; i < 32 * 64 * 512; i += stride) {
        int k = i & 511, r = (i >> 9) & 63, m = i >> 15;
        int row = (r >> 4) * HID + m * UPW + (r & 15);
        W0p[i] = __float2bfloat16(Whh0[(size_t)row * HID + k]);
    }
    __hip_bfloat16* W1p = (__hip_bfloat16*)(ws + OFF_W1);
    for (int i = tid; i < 32 * 64 * 1024; i += stride) {
        int k = i & 1023, r = (i >> 10) & 63, m = i >> 16;
        int row = (r >> 4) * HID + m * UPW + (r & 15);
        float v = (k < 512) ? Wih1[(size_t)row * HID + k] : Whh1[(size_t)row * HID + (k - 512)];
        W1p[i] = __float2bfloat16(v);
    }
    float* wi = (float*)(ws + OFF_WI);
    float* b0 = (float*)(ws + OFF_B0);
    float* b1 = (float*)(ws + OFF_B1);
    for (int i = tid; i < 32 * 64; i += stride) {
        int r = i & 63, m = i >> 6;
        int row = (r >> 4) * HID + m * UPW + (r & 15);
        wi[i] = Wih0[row];                  // IN = 1
        b0[i] = bih0[row] + bhh0[row];
        b1[i] = bih1[row] + bhh1[row];
    }
    float* xT = (float*)(ws + OFF_XT);      // [T][B] for coalesced step reads
    for (int i = tid; i < TLEN * BATCH; i += stride) {
        int t = i >> 8, b = i & 255;
        xT[i] = x[(size_t)b * TLEN + t];
    }
}

__global__ __launch_bounds__(256, 1) void lstm_persist(
    const float* __restrict__ wlin,
    float* __restrict__ out, char* __restrict__ ws)
{
    const int tid  = threadIdx.x;
    const int lane = tid & 63;
    const int wave = tid >> 6;
    const int g    = blockIdx.x & 7;   // group -> XCD swizzle
    const int m    = blockIdx.x >> 3;  // member within group: unit slice
    const int bbase = g * BPG;

    __shared__ __attribute__((aligned(16))) __hip_bfloat16 As[32 * ROWP]; // staged [h0|h1] rows
    __shared__ float gatesS[32][68];

    // zero As (t=0 reads h0prev=0 from it)
    {
        int* az = (int*)As;
        for (int i = tid; i < (32 * ROWP * 2) / 4; i += 256) az[i] = 0;
    }

    const float* wis = (const float*)(ws + OFF_WI) + m * NR;
    const float* b0s = (const float*)(ws + OFF_B0) + m * NR;
    const float* b1s = (const float*)(ws + OFF_B1) + m * NR;
    // CA layout: [g][parity][half][m][b][us] bf16; region(m) = 32*16*2 = 1024 B
    char* CAg = ws + OFF_CA + (size_t)g * 131072;
    float* xfeed = (float*)(ws + OFF_XF);
    const float* xT = (const float*)(ws + OFF_XT);
    unsigned* flags = (unsigned*)(ws + OFF_BAR) + g * 64;

    const int fl = lane & 15;          // n sub-index in fragment
    const int fq = lane >> 4;          // quad (k sub-chunk)
    const int w  = wave;               // wave = gate tile, 0..3
    const int us  = tid & 15;          // unit within slice (elementwise)
    const int b0r = tid >> 4;          // batch row 0..15
    const int b1r = b0r + 16;

    // per-thread constants in registers
    const float wl0 = wlin[m * UPW + us];
    float wiR[4], b0R[4], b1R[4];
#pragma unroll
    for (int q = 0; q < 4; ++q) {
        wiR[q] = wis[q * 16 + us];
        b0R[q] = b0s[q * 16 + us];
        b1R[q] = b1s[q * 16 + us];
    }
    float c00 = 0.f, c01 = 0.f, c10 = 0.f, c11 = 0.f;  // cell state regs

    // publish byte offsets within a parity buffer (region m, idx b*16+us)
    const int pub_h0  = m * 1024 + tid * 2;            // b0r half (idx=tid)
    const int pub_h1  = 32768 + m * 1024 + tid * 2;    // layer-1 half
    // DMA per-lane gather offset: lane j -> region m=j>>1, sub-chunk (j&1)*16
    const int dmaLane = (lane >> 1) * 1024 + (lane & 1) * 16;

    // ---- load this wave's weight slice into registers (192 VGPRs/lane) ----
    const bf16x8* W0row = (const bf16x8*)(ws + OFF_W0 + (size_t)m * NR * 512 * 2)
                          + (size_t)(w * 16 + fl) * 64;
    const bf16x8* W1row = (const bf16x8*)(ws + OFF_W1 + (size_t)m * NR * 1024 * 2)
                          + (size_t)(w * 16 + fl) * 128;
    bf16x8 w0f[16], w1f[32];
#pragma unroll
    for (int ks = 0; ks < 16; ++ks) w0f[ks] = W0row[ks * 4 + fq];
#pragma unroll
    for (int ks = 0; ks < 32; ++ks) w1f[ks] = W1row[ks * 4 + fq];

    __syncthreads();  // As zeroed before use

    unsigned phase = 0;
    for (int t = 0; t < NSTEP; ++t) {
        const int p = t & 1;
        char* CAp = CAg + p * 65536;          // this step's parity (h0/h1 writes)
        char* CAq = CAg + (1 - p) * 65536;    // previous parity (h1prev reads)

        // prefetch x / feedback early (coalesced via xT; overlaps L0 GEMM)
        float xv0, xv1;
        if (t < TLEN) {
            xv0 = xT[t * BATCH + bbase + b0r];
            xv1 = xT[t * BATCH + bbase + b1r];
        } else {
            xv0 = xfeed[(t - TLEN) * BATCH + bbase + b0r];
            xv1 = xfeed[(t - TLEN) * BATCH + bbase + b1r];
        }

        // ---------------- layer 0 GEMM from LDS (h0prev in As cols [0,512))
        f32x4 acc0 = {0.f, 0.f, 0.f, 0.f}, acc1 = {0.f, 0.f, 0.f, 0.f};
        {
            const bf16x8* a0p = (const bf16x8*)&As[(size_t)fl * ROWP];
            const bf16x8* a1p = (const bf16x8*)&As[(size_t)(16 + fl) * ROWP];
#pragma unroll
            for (int ks = 0; ks < 16; ++ks) {
                bf16x8 a0 = a0p[ks * 4 + fq];
                bf16x8 a1 = a1p[ks * 4 + fq];
                acc0 = __builtin_amdgcn_mfma_f32_16x16x32_bf16(a0, w0f[ks], acc0, 0, 0, 0);
                acc1 = __builtin_amdgcn_mfma_f32_16x16x32_bf16(a1, w0f[ks], acc1, 0, 0, 0);
            }
        }
#pragma unroll
        for (int i = 0; i < 4; ++i) {   // C layout: m = quad*4+reg, n = lane&15
            gatesS[fq * 4 + i][w * 16 + fl]      = acc0[i];
            gatesS[16 + fq * 4 + i][w * 16 + fl] = acc1[i];
        }
        __syncthreads();

        // ---------------- layer 0 elementwise (state in regs), publish h0 via LLC
        {
            float gi = gatesS[b0r][us]      + b0R[0] + xv0 * wiR[0];
            float gf = gatesS[b0r][16 + us] + b0R[1] + xv0 * wiR[1];
            float gg = gatesS[b0r][32 + us] + b0R[2] + xv0 * wiR[2];
            float go = gatesS[b0r][48 + us] + b0R[3] + xv0 * wiR[3];
            c00 = sigf(gf) * c00 + sigf(gi) * tanh_fast(gg);
            __hip_bfloat16 h = __float2bfloat16(sigf(go) * tanh_fast(c00));
            store_short_llc(CAp + pub_h0, *(unsigned short*)&h);
        }
        {
            float gi = gatesS[b1r][us]      + b0R[0] + xv1 * wiR[0];
            float gf = gatesS[b1r][16 + us] + b0R[1] + xv1 * wiR[1];
            float gg = gatesS[b1r][32 + us] + b0R[2] + xv1 * wiR[2];
            float go = gatesS[b1r][48 + us] + b0R[3] + xv1 * wiR[3];
            c01 = sigf(gf) * c01 + sigf(gi) * tanh_fast(gg);
            __hip_bfloat16 h = __float2bfloat16(sigf(go) * tanh_fast(c01));
            store_short_llc(CAp + pub_h0 + 512, *(unsigned short*)&h);
        }

        ++phase;
        flag_barrier(flags, m, phase);   // h0 publish visible at LLC -> all WGs

        // ---------------- stage [h0new | h1prev] -> LDS As via LLC-coherent DMA
        {
            char* AsB = (char*)As;
#pragma unroll
            for (int ci = 0; ci < 8; ++ci) {
                int b = wave * 8 + ci;
                gl2lds16_llc(CAp + b * 32 + dmaLane,         AsB + b * 2064);         // h0 new
                gl2lds16_llc(CAq + 32768 + b * 32 + dmaLane, AsB + b * 2064 + 1024);  // h1 prev
            }
            __builtin_amdgcn_s_waitcnt(0);
            __syncthreads();
        }

        // ---------------- layer 1 GEMM: K=1024 over staged [h0new | h1prev]
        acc0 = (f32x4){0.f, 0.f, 0.f, 0.f};
        acc1 = (f32x4){0.f, 0.f, 0.f, 0.f};
        {
            const bf16x8* a0p = (const bf16x8*)&As[(size_t)fl * ROWP];
            const bf16x8* a1p = (const bf16x8*)&As[(size_t)(16 + fl) * ROWP];
#pragma unroll
            for (int ks = 0; ks < 32; ++ks) {
                bf16x8 a0 = a0p[ks * 4 + fq];
                bf16x8 a1 = a1p[ks * 4 + fq];
                acc0 = __builtin_amdgcn_mfma_f32_16x16x32_bf16(a0, w1f[ks], acc0, 0, 0, 0);
                acc1 = __builtin_amdgcn_mfma_f32_16x16x32_bf16(a1, w1f[ks], acc1, 0, 0, 0);
            }
        }
#pragma unroll
        for (int i = 0; i < 4; ++i) {
            gatesS[fq * 4 + i][w * 16 + fl]      = acc0[i];
            gatesS[16 + fq * 4 + i][w * 16 + fl] = acc1[i];
        }
        __syncthreads();

        // ---------------- layer 1 elementwise + OUT=1 linear, publish h1 via LLC
        {
            float gi = gatesS[b0r][us]      + b1R[0];
            float gf = gatesS[b0r][16 + us] + b1R[1];
            float gg = gatesS[b0r][32 + us] + b1R[2];
            float go = gatesS[b0r][48 + us] + b1R[3];
            c10 = sigf(gf) * c10 + sigf(gi) * tanh_fast(gg);
            float h = sigf(go) * tanh_fast(c10);
            __hip_bfloat16 hb = __float2bfloat16(h);
            store_short_llc(CAp + pub_h1, *(unsigned short*)&hb);
            float po = wl0 * h;
#pragma unroll
            for (int off = 1; off < 16; off <<= 1) po += __shfl_xor(po, off, 64);
            if (us == 0) {
                atomicAdd(&out[(size_t)(bbase + b0r) * NSTEP + t], po);
                if (t >= TLEN - 1)
                    atomicAdd(&xfeed[(t - (TLEN - 1)) * BATCH + bbase + b0r], po);
            }
        }
        {
            float gi = gatesS[b1r][us]      + b1R[0];
            float gf = gatesS[b1r][16 + us] + b1R[1];
            float gg = gatesS[b1r][32 + us] + b1R[2];
            float go = gatesS[b1r][48 + us] + b1R[3];
            c11 = sigf(gf) * c11 + sigf(gi) * tanh_fast(gg);
            float h = sigf(go) * tanh_fast(c11);
            __hip_bfloat16 hb = __float2bfloat16(h);
            store_short_llc(CAp + pub_h1 + 512, *(unsigned short*)&hb);
            float po = wl0 * h;
#pragma unroll
            for (int off = 1; off < 16; off <<= 1) po += __shfl_xor(po, off, 64);
            if (us == 0) {
                atomicAdd(&out[(size_t)(bbase + b1r) * NSTEP + t], po);
                if (t >= TLEN - 1)
                    atomicAdd(&xfeed[(t - (TLEN - 1)) * BATCH + bbase + b1r], po);
            }
        }

        // 2nd barrier only needed to order xfeed publish -> next step's read
        if (t >= TLEN - 1) {
            ++phase;
            flag_barrier(flags, m, phase);
        } else {
            __syncthreads();   // gatesS reuse guard within WG
        }
    }
}

extern "C" void kernel_launch(void* const* d_in, const int* in_sizes, int n_in,
                              void* d_out, int out_size, void* d_ws, size_t ws_size,
                              hipStream_t stream)
{
    const float* x    = (const float*)d_in[0];
    const float* Wih0 = (const float*)d_in[1];
    const float* Whh0 = (const float*)d_in[2];
    const float* bih0 = (const float*)d_in[3];
    const float* bhh0 = (const float*)d_in[4];
    const float* Wih1 = (const float*)d_in[5];
    const float* Whh1 = (const float*)d_in[6];
    const float* bih1 = (const float*)d_in[7];
    const float* bhh1 = (const float*)d_in[8];
    const float* Wlin = (const float*)d_in[9];
    const float* blin = (const float*)d_in[10];
    float* out = (float*)d_out;
    char* ws = (char*)d_ws;

    hipLaunchKernelGGL(lstm_init, dim3(256), dim3(256), 0, stream, ws, out, blin);
    hipLaunchKernelGGL(lstm_pack, dim3(512), dim3(256), 0, stream,
                       ws, x, Wih0, Whh0, bih0, bhh0, Wih1, Whh1, bih1, bhh1);
    hipLaunchKernelGGL(lstm_persist, dim3(256), dim3(256), 0, stream, Wlin, out, ws);
}